// Round 1
// baseline (46.371 us; speedup 1.0000x reference)
//
#include <hip/hip_runtime.h>

#define C_ 128
#define K_ 64
#define H_ 40
#define W_ 30
#define N_ 4
#define HW_ 1200          // H_*W_
#define P_ 5
#define OH_ 36            // H_+1-P_
#define OW_ 26            // W_+1-P_
#define OHW_ 936

// DPP helper: returns value moved per CTRL, 0-filled at row bounds.
// row_shl:N = 0x100+N  -> lane i gets lane i+N (within 16-lane row)
// row_shr:N = 0x110+N  -> lane i gets lane i-N (within 16-lane row)
template<int CTRL>
__device__ __forceinline__ float dpp0f(float v) {
  return __int_as_float(__builtin_amdgcn_update_dpp(
      0, __float_as_int(v), CTRL, 0xF, 0xF, true));
}
// swap 16-lane rows pairwise (lane ^= 16)
__device__ __forceinline__ float swz_x16(float v) {
  return __int_as_float(__builtin_amdgcn_ds_swizzle(__float_as_int(v), 0x401F));
}

// ---------------------------------------------------------------------------
// K1: per-pixel L2 norm over C, 1x1 conv (K=64), softmax -> xn, sa
// block = 256 threads, 32 pixels per block; grid = 4800/32 = 150
// ---------------------------------------------------------------------------
__global__ __launch_bounds__(256) void k1_prep(
    const float* __restrict__ x, const float* __restrict__ cw,
    float* __restrict__ xn, float* __restrict__ sa)
{
  __shared__ float xs[C_][32];      // 16 KB  x values, [c][pixel]
  __shared__ float wt[C_][K_];      // 32 KB  conv_w transposed
  __shared__ float part[8][32];     // partial norm sums
  __shared__ float ls[K_][32];      // logits then exp values
  __shared__ float rnorm_s[32];
  __shared__ float rsum_s[32];

  const int tid  = threadIdx.x;
  const int pix0 = blockIdx.x << 5;

  // stage conv_w transposed: wt[c][k] = cw[k*C_+c]
  for (int e = tid; e < C_*K_; e += 256) {
    const int c = e >> 6, kk = e & 63;
    wt[c][kk] = cw[kk*C_ + c];
  }
  // stage x for 32 pixels
  for (int e = tid; e < C_*32; e += 256) {
    const int c = e >> 5, pl = e & 31;
    const int pix = pix0 + pl;
    const int n = pix / HW_, rem = pix - n*HW_;
    xs[c][pl] = x[(size_t)(n*C_ + c)*HW_ + rem];
  }
  __syncthreads();
  // partial norms: thread (cq,pl) sums 16 channels
  {
    const int pl = tid & 31, cq = tid >> 5;
    float s = 0.f;
    #pragma unroll
    for (int cc = 0; cc < 16; ++cc) {
      const float v = xs[cq*16 + cc][pl];
      s = fmaf(v, v, s);
    }
    part[cq][pl] = s;
  }
  __syncthreads();
  if (tid < 32) {
    float s = 0.f;
    #pragma unroll
    for (int qq = 0; qq < 8; ++qq) s += part[qq][tid];
    rnorm_s[tid] = 1.f / fmaxf(sqrtf(s), 1e-12f);
  }
  __syncthreads();
  // 1x1 conv: thread (kq,pl) computes 8 k's for its pixel
  {
    const int pl = tid & 31, kq = tid >> 5;
    float acc[8];
    #pragma unroll
    for (int qq = 0; qq < 8; ++qq) acc[qq] = 0.f;
    for (int c = 0; c < C_; ++c) {
      const float xv = xs[c][pl];
      const float4 w0 = *(const float4*)&wt[c][kq*8];
      const float4 w1 = *(const float4*)&wt[c][kq*8 + 4];
      acc[0] = fmaf(xv, w0.x, acc[0]);
      acc[1] = fmaf(xv, w0.y, acc[1]);
      acc[2] = fmaf(xv, w0.z, acc[2]);
      acc[3] = fmaf(xv, w0.w, acc[3]);
      acc[4] = fmaf(xv, w1.x, acc[4]);
      acc[5] = fmaf(xv, w1.y, acc[5]);
      acc[6] = fmaf(xv, w1.z, acc[6]);
      acc[7] = fmaf(xv, w1.w, acc[7]);
    }
    const float rn = rnorm_s[pl];
    #pragma unroll
    for (int qq = 0; qq < 8; ++qq) ls[kq*8 + qq][pl] = acc[qq] * rn;
  }
  __syncthreads();
  // softmax over K per pixel (32 threads)
  if (tid < 32) {
    const int pl = tid;
    float m = -1e30f;
    for (int kk = 0; kk < K_; ++kk) m = fmaxf(m, ls[kk][pl]);
    float s = 0.f;
    for (int kk = 0; kk < K_; ++kk) {
      const float e = expf(ls[kk][pl] - m);
      ls[kk][pl] = e;
      s += e;
    }
    rsum_s[pl] = 1.f / s;
  }
  __syncthreads();
  // write sa
  for (int e = tid; e < K_*32; e += 256) {
    const int kk = e >> 5, pl = e & 31;
    const int pix = pix0 + pl;
    const int n = pix / HW_, rem = pix - n*HW_;
    sa[(size_t)(n*K_ + kk)*HW_ + rem] = ls[kk][pl] * rsum_s[pl];
  }
  // write xn
  for (int e = tid; e < C_*32; e += 256) {
    const int c = e >> 5, pl = e & 31;
    const int pix = pix0 + pl;
    const int n = pix / HW_, rem = pix - n*HW_;
    xn[(size_t)(n*C_ + c)*HW_ + rem] = xs[c][pl] * rnorm_s[pl];
  }
}

// ---------------------------------------------------------------------------
// K2: out[n, k*C+c, i, j] = box5x5((xn[c]-cent[k,c])*sa[k]) / 25
// thread = (c, w): q[h] over 40 rows in regs; vertical window via register
// slide; horizontal 5-sum across lanes via DPP + ds_swizzle(xor16).
// wave = 2 c's x 32 lanes (w=0..29 valid). block = 8 c's. grid = (16,64,4).
// ---------------------------------------------------------------------------
__global__ __launch_bounds__(256) void k2_box(
    const float* __restrict__ xn, const float* __restrict__ sa,
    const float* __restrict__ cent, float* __restrict__ out)
{
  const int tid = threadIdx.x;
  const int w   = tid & 31;
  const int wc  = (w < W_) ? w : (W_ - 1);   // clamp pad lanes 30,31
  const int c   = (blockIdx.x << 3) + (tid >> 5);
  const int k   = blockIdx.y;
  const int n   = blockIdx.z;

  const float cv = cent[k*C_ + c];
  const float* __restrict__ xp = xn + (size_t)(n*C_ + c)*HW_ + wc;
  const float* __restrict__ sp = sa + (size_t)(n*K_ + k)*HW_ + wc;

  float q[H_];
  #pragma unroll
  for (int h = 0; h < H_; ++h) {
    q[h] = (xp[h*W_] - cv) * sp[h*W_];
  }

  float vq = q[0] + q[1] + q[2] + q[3] + q[4];  // vertical 5-window sum
  float* __restrict__ op = out + (size_t)((n*K_ + k)*C_ + c)*OHW_ + w;

  #pragma unroll
  for (int i = 0; i < OH_; ++i) {
    // hs[w] = sum_{d=0..4} vq[w+d]; in-row part via row_shl:d, cross-row
    // part via swz(x16) + row_shr:(16-d). Pollution only hits lanes w>=26.
    const float sw = swz_x16(vq);
    float hs = vq;
    hs += dpp0f<0x101>(vq) + dpp0f<0x11F>(sw);  // d=1
    hs += dpp0f<0x102>(vq) + dpp0f<0x11E>(sw);  // d=2
    hs += dpp0f<0x103>(vq) + dpp0f<0x11D>(sw);  // d=3
    hs += dpp0f<0x104>(vq) + dpp0f<0x11C>(sw);  // d=4
    if (w < OW_) op[i*OW_] = hs * (1.f / (P_*P_));
    if (i < OH_ - 1) vq += q[i + P_] - q[i];
  }
}

extern "C" void kernel_launch(void* const* d_in, const int* in_sizes, int n_in,
                              void* d_out, int out_size, void* d_ws, size_t ws_size,
                              hipStream_t stream) {
  const float* x  = (const float*)d_in[0];
  const float* cw = (const float*)d_in[1];  // [K,C]
  const float* ce = (const float*)d_in[2];  // [K,C]
  // d_in[3]=patch_size(5), d_in[4]=stride(1): fixed by setup, hardcoded.

  float* xn = (float*)d_ws;                 // 4*128*1200 = 614400 f32
  float* sa = xn + (size_t)N_*C_*HW_;       // 4*64*1200  = 307200 f32
  float* out = (float*)d_out;               // 4*8192*36*26 f32

  k1_prep<<<dim3(150), dim3(256), 0, stream>>>(x, cw, xn, sa);
  k2_box<<<dim3(C_/8, K_, N_), dim3(256), 0, stream>>>(xn, sa, ce, out);
}